// Round 2
// baseline (856.709 us; speedup 1.0000x reference)
//
#include <hip/hip_runtime.h>

#define CCH 64  // channels
#define SCAN_T 1024

// ---------------- fill deg with 1.0 (self-loop) ----------------
__global__ void k_fill1(float* __restrict__ p, int n) {
    int i = blockIdx.x * blockDim.x + threadIdx.x;
    if (i < n) p[i] = 1.0f;
}

// ---------------- degree count: deg[dst] += 1 ----------------
__global__ void k_deg(const int* __restrict__ dst, float* __restrict__ deg, int E) {
    int e = blockIdx.x * blockDim.x + threadIdx.x;
    if (e < E) atomicAdd(&deg[dst[e]], 1.0f);
}

// ---------------- dinv = rsqrt(deg) in place ----------------
__global__ void k_rsqrt(float* __restrict__ p, int n) {
    int i = blockIdx.x * blockDim.x + threadIdx.x;
    if (i < n) p[i] = rsqrtf(p[i]);
}

// ---------------- exclusive scan of (deg-1) -> row_start + pos ------------
// one 1024-thread block per conv (blockIdx.x = conv id). deg laid out as
// 3 contiguous arrays of N floats; rs as 3 x (N+1) ints; pos as 3 x N ints.
__global__ void __launch_bounds__(SCAN_T) k_scan(const float* __restrict__ deg,
                                                 int* __restrict__ rs,
                                                 int* __restrict__ pos, int N) {
    int c = blockIdx.x;
    const float* d = deg + (size_t)c * N;
    int* rsc  = rs  + (size_t)c * (N + 1);
    int* posc = pos + (size_t)c * N;
    __shared__ int part[SCAN_T];
    int t = threadIdx.x;
    int chunk = (N + SCAN_T - 1) / SCAN_T;
    int lo = t * chunk;
    int hi = lo + chunk; if (hi > N) hi = N; if (lo > N) lo = N;
    int s = 0;
    for (int i = lo; i < hi; ++i) s += (int)d[i] - 1;   // self-loop excluded
    part[t] = s;
    __syncthreads();
    // Hillis-Steele inclusive scan over 1024 partials
    for (int off = 1; off < SCAN_T; off <<= 1) {
        int v = (t >= off) ? part[t - off] : 0;
        __syncthreads();
        part[t] += v;
        __syncthreads();
    }
    int run = (t == 0) ? 0 : part[t - 1];               // exclusive prefix
    for (int i = lo; i < hi; ++i) {
        rsc[i] = run;
        posc[i] = run;
        run += (int)d[i] - 1;
    }
    if (t == SCAN_T - 1) rsc[N] = run;                  // == E
}

// ---------------- CSR slot fill: sidx[pos[dst]++] = src ----------------
__global__ void k_fill_csr(const int* __restrict__ src, const int* __restrict__ dst,
                           int* __restrict__ pos, int* __restrict__ sidx, int E) {
    int e = blockIdx.x * blockDim.x + threadIdx.x;
    if (e < E) {
        int slot = atomicAdd(&pos[dst[e]], 1);
        sidx[slot] = src[e];
    }
}

// ---------------- h[N,64] = x[N,64] @ W[64,64] ----------------
__global__ void __launch_bounds__(256) k_gemm(const float* __restrict__ x,
                                              const float* __restrict__ W,
                                              float* __restrict__ h, int N) {
    __shared__ float Ws[CCH * CCH];
    __shared__ float xs[4 * CCH];
    int tid = threadIdx.x;
    for (int i = tid; i < CCH * CCH; i += 256) Ws[i] = W[i];
    int r = tid >> 6;
    int c = tid & 63;
    int row = blockIdx.x * 4 + r;
    if (row < N) xs[tid] = x[row * CCH + c];
    __syncthreads();
    if (row < N) {
        float acc = 0.0f;
        #pragma unroll
        for (int k = 0; k < CCH; ++k) acc += xs[r * CCH + k] * Ws[k * CCH + c];
        h[row * CCH + c] = acc;
    }
}

// ------- out_star init: b1 + b2 + h1*d1^2 + h2*d2^2 (self-loops + bias) ----
__global__ void k_init_star(const float* __restrict__ h1, const float* __restrict__ d1,
                            const float* __restrict__ h2, const float* __restrict__ d2,
                            const float* __restrict__ b1, const float* __restrict__ b2,
                            float* __restrict__ out, int total) {
    int t = blockIdx.x * blockDim.x + threadIdx.x;
    if (t < total) {
        int i = t >> 6, c = t & 63;
        float w1 = d1[i], w2 = d2[i];
        out[t] = b1[c] + b2[c] + h1[t] * (w1 * w1) + h2[t] * (w2 * w2);
    }
}

__global__ void k_init_gal(const float* __restrict__ h, const float* __restrict__ d,
                           const float* __restrict__ b,
                           float* __restrict__ out, int total) {
    int t = blockIdx.x * blockDim.x + threadIdx.x;
    if (t < total) {
        int i = t >> 6, c = t & 63;
        float w = d[i];
        out[t] = b[c] + h[t] * (w * w);
    }
}

// ---------------- pull: one wave per dst row, lane = channel ----------------
// out[d,:] += sum_{e in CSR(d)} h[src_e,:] * dinv[src_e] * dinv[d]
__global__ void __launch_bounds__(256) k_pull(const int* __restrict__ rs,
                                              const int* __restrict__ sidx,
                                              const float* __restrict__ h,
                                              const float* __restrict__ dinv,
                                              float* __restrict__ out, int N) {
    int w = blockIdx.x * 4 + (threadIdx.x >> 6);
    if (w >= N) return;
    int lane = threadIdx.x & 63;
    int beg = rs[w], end = rs[w + 1];
    float dd = dinv[w];
    float acc = 0.0f;
    int i = beg;
    for (; i + 1 < end; i += 2) {   // 2-edge unroll: 2 independent gather chains
        int s0 = sidx[i], s1 = sidx[i + 1];
        float w0 = dinv[s0] * dd;
        float w1 = dinv[s1] * dd;
        acc += h[(size_t)s0 * CCH + lane] * w0;
        acc += h[(size_t)s1 * CCH + lane] * w1;
    }
    if (i < end) {
        int s0 = sidx[i];
        acc += h[(size_t)s0 * CCH + lane] * (dinv[s0] * dd);
    }
    out[(size_t)w * CCH + lane] += acc;
}

extern "C" void kernel_launch(void* const* d_in, const int* in_sizes, int n_in,
                              void* d_out, int out_size, void* d_ws, size_t ws_size,
                              hipStream_t stream) {
    const float* x_star = (const float*)d_in[0];
    const float* x_gal  = (const float*)d_in[1];
    const int*   e_ssn  = (const int*)d_in[2];
    const int*   e_ssf  = (const int*)d_in[3];
    const int*   e_ggn  = (const int*)d_in[4];
    const float* W_ssn  = (const float*)d_in[5];
    const float* W_ssf  = (const float*)d_in[6];
    const float* W_ggn  = (const float*)d_in[7];
    const float* b_ssn  = (const float*)d_in[8];
    const float* b_ssf  = (const float*)d_in[9];
    const float* b_ggn  = (const float*)d_in[10];

    const int N  = in_sizes[0] / CCH;   // 50000
    const int E  = in_sizes[2] / 2;     // 1000000
    const int NC = N * CCH;

    float* out_star = (float*)d_out;
    float* out_gal  = out_star + NC;

    // workspace layout
    float* ws    = (float*)d_ws;
    float* h0    = ws;                  // 3 x NC floats
    float* h1    = ws + (size_t)NC;
    float* h2    = ws + (size_t)2 * NC;
    float* dinv0 = ws + (size_t)3 * NC; // 3 x N floats (deg -> dinv in place)
    float* dinv1 = dinv0 + N;
    float* dinv2 = dinv1 + N;
    int*   rs    = (int*)(dinv2 + N);   // 3 x (N+1) ints
    int*   pos   = rs + 3 * (N + 1);    // 3 x N ints
    int*   sidx0 = pos + 3 * N;         // 3 x E ints
    int*   sidx1 = sidx0 + E;
    int*   sidx2 = sidx1 + E;

    const int B = 256;
    int eblk = (E + B - 1) / B;

    // 1) deg init (self-loop = 1.0)
    k_fill1<<<(3 * N + B - 1) / B, B, 0, stream>>>(dinv0, 3 * N);

    // 2) degree histogram at dst
    k_deg<<<eblk, B, 0, stream>>>(e_ssn + E, dinv0, E);
    k_deg<<<eblk, B, 0, stream>>>(e_ssf + E, dinv1, E);
    k_deg<<<eblk, B, 0, stream>>>(e_ggn + E, dinv2, E);

    // 3) CSR offsets from integer (deg-1); also primes pos[]
    k_scan<<<3, SCAN_T, 0, stream>>>(dinv0, rs, pos, N);

    // 4) dinv = rsqrt(deg)  (after scan reads deg)
    k_rsqrt<<<(3 * N + B - 1) / B, B, 0, stream>>>(dinv0, 3 * N);

    // 5) CSR slot fill (only needs dst + pos)
    k_fill_csr<<<eblk, B, 0, stream>>>(e_ssn, e_ssn + E, pos,             sidx0, E);
    k_fill_csr<<<eblk, B, 0, stream>>>(e_ssf, e_ssf + E, pos + N,         sidx1, E);
    k_fill_csr<<<eblk, B, 0, stream>>>(e_ggn, e_ggn + E, pos + 2 * N,     sidx2, E);

    // 6) dense transforms h = x @ W
    int gblk = (N + 3) / 4;
    k_gemm<<<gblk, B, 0, stream>>>(x_star, W_ssn, h0, N);
    k_gemm<<<gblk, B, 0, stream>>>(x_star, W_ssf, h1, N);
    k_gemm<<<gblk, B, 0, stream>>>(x_gal,  W_ggn, h2, N);

    // 7) init outputs: bias + self-loop contribution
    k_init_star<<<(NC + B - 1) / B, B, 0, stream>>>(h0, dinv0, h1, dinv1,
                                                    b_ssn, b_ssf, out_star, NC);
    k_init_gal<<<(NC + B - 1) / B, B, 0, stream>>>(h2, dinv2, b_ggn, out_gal, NC);

    // 8) pull-accumulate per dst row (no atomics)
    int pblk = (N + 3) / 4;
    k_pull<<<pblk, B, 0, stream>>>(rs,               sidx0, h0, dinv0, out_star, N);
    k_pull<<<pblk, B, 0, stream>>>(rs + (N + 1),     sidx1, h1, dinv1, out_star, N);
    k_pull<<<pblk, B, 0, stream>>>(rs + 2 * (N + 1), sidx2, h2, dinv2, out_gal,  N);
}

// Round 3
// 650.165 us; speedup vs baseline: 1.3177x; 1.3177x over previous
//
#include <hip/hip_runtime.h>

#define CCH 64  // channels

// ---------------- zero int buffer ----------------
__global__ void k_zero(int* __restrict__ p, int n) {
    int i = blockIdx.x * blockDim.x + threadIdx.x;
    if (i < n) p[i] = 0;
}

// ---------------- degree histogram for all 3 convs ----------------
__global__ void k_deg_all(const int* __restrict__ e0, const int* __restrict__ e1,
                          const int* __restrict__ e2, int* __restrict__ deg,
                          int E, int N) {
    int t = blockIdx.x * blockDim.x + threadIdx.x;
    if (t >= 3 * E) return;
    int c = (t >= 2 * E) ? 2 : (t >= E) ? 1 : 0;
    int e = t - c * E;
    const int* ed = (c == 0) ? e0 : (c == 1) ? e1 : e2;
    atomicAdd(&deg[c * N + ed[E + e]], 1);
}

// ---- scanA: per-block (1024 elems) scan of deg; also dinv=rsqrt(deg+1) ----
// rs stride per conv is N+4 (keeps 16B alignment for int4 stores).
__global__ void __launch_bounds__(256) k_scanA(const int* __restrict__ deg,
        float* __restrict__ dinv, int* __restrict__ rs, int* __restrict__ pos,
        int* __restrict__ bsum, int N, int nb) {
    int c = blockIdx.x / nb;
    int blk = blockIdx.x - c * nb;
    int t = threadIdx.x;
    int i0 = blk * 1024 + t * 4;
    const int* dg = deg + c * N;
    int d0 = 0, d1 = 0, d2 = 0, d3 = 0;
    if (i0 + 3 < N) {
        int4 v = *(const int4*)(dg + i0);
        d0 = v.x; d1 = v.y; d2 = v.z; d3 = v.w;
    } else if (i0 < N) {
        d0 = dg[i0];
        if (i0 + 1 < N) d1 = dg[i0 + 1];
        if (i0 + 2 < N) d2 = dg[i0 + 2];
    }
    __shared__ int sm[256];
    sm[t] = d0 + d1 + d2 + d3;
    __syncthreads();
    #pragma unroll
    for (int off = 1; off < 256; off <<= 1) {
        int v = (t >= off) ? sm[t - off] : 0;
        __syncthreads();
        sm[t] += v;
        __syncthreads();
    }
    int run = (t == 0) ? 0 : sm[t - 1];
    int* rsc = rs + c * (N + 4);
    int* posc = pos + c * N;
    float* dvc = dinv + c * N;
    if (i0 + 3 < N) {
        int4 rv;
        rv.x = run; rv.y = run + d0; rv.z = run + d0 + d1; rv.w = run + d0 + d1 + d2;
        *(int4*)(rsc + i0) = rv;
        *(int4*)(posc + i0) = rv;
        float4 dv;
        dv.x = rsqrtf((float)(d0 + 1)); dv.y = rsqrtf((float)(d1 + 1));
        dv.z = rsqrtf((float)(d2 + 1)); dv.w = rsqrtf((float)(d3 + 1));
        *(float4*)(dvc + i0) = dv;
    } else if (i0 < N) {
        int r = run;
        rsc[i0] = r; posc[i0] = r; dvc[i0] = rsqrtf((float)(d0 + 1)); r += d0;
        if (i0 + 1 < N) { rsc[i0+1] = r; posc[i0+1] = r; dvc[i0+1] = rsqrtf((float)(d1 + 1)); r += d1; }
        if (i0 + 2 < N) { rsc[i0+2] = r; posc[i0+2] = r; dvc[i0+2] = rsqrtf((float)(d2 + 1)); }
    }
    if (t == 255) bsum[blockIdx.x] = sm[255];
}

// ---- scanB: exclusive scan of the <=64 block sums per conv (wave per conv) ----
__global__ void k_scanB(int* __restrict__ bsum, int* __restrict__ rs,
                        int nb, int N, int E) {
    int wv = threadIdx.x >> 6;   // conv 0..2  (launched with 192 threads)
    int l = threadIdx.x & 63;
    int orig = (l < nb) ? bsum[wv * nb + l] : 0;
    int v = orig;
    #pragma unroll
    for (int off = 1; off < 64; off <<= 1) {
        int u = __shfl_up(v, off, 64);
        if (l >= off) v += u;
    }
    if (l < nb) bsum[wv * nb + l] = v - orig;   // exclusive prefix
    if (l == 0) rs[wv * (N + 4) + N] = E;       // row_start[N] = total edges
}

// ---- scanC: add per-block offset to rs/pos ----
__global__ void __launch_bounds__(256) k_scanC(int* __restrict__ rs,
        int* __restrict__ pos, const int* __restrict__ bsum, int N, int nb) {
    int c = blockIdx.x / nb;
    int blk = blockIdx.x - c * nb;
    int add = bsum[c * nb + blk];
    if (add == 0) return;
    int t = threadIdx.x;
    int i0 = blk * 1024 + t * 4;
    int* rsc = rs + c * (N + 4);
    int* posc = pos + c * N;
    if (i0 + 3 < N) {
        int4 r = *(int4*)(rsc + i0);
        r.x += add; r.y += add; r.z += add; r.w += add;
        *(int4*)(rsc + i0) = r;
        *(int4*)(posc + i0) = r;   // pos content == rs content at this stage
    } else if (i0 < N) {
        for (int j = 0; j < 3 && i0 + j < N; ++j) {
            int r = rsc[i0 + j] + add;
            rsc[i0 + j] = r; posc[i0 + j] = r;
        }
    }
}

// ---- h'[c,row,:] = (x_row . W_c) * dinv[c,row]  (pre-scaled transform) ----
// 16 rows/block, W + x tile in LDS; wave = 4 rows, lane = column.
__global__ void __launch_bounds__(256) k_gemm_all(const float* __restrict__ xs_,
        const float* __restrict__ xg_, const float* __restrict__ W0,
        const float* __restrict__ W1, const float* __restrict__ W2,
        const float* __restrict__ dinv, float* __restrict__ h, int N) {
    int c = blockIdx.y;
    const float* x = (c == 2) ? xg_ : xs_;
    const float* W = (c == 0) ? W0 : (c == 1) ? W1 : W2;
    __shared__ float Ws[CCH * CCH];
    __shared__ float xsm[16 * CCH];
    int t = threadIdx.x;
    #pragma unroll
    for (int j = 0; j < 4; ++j) {
        int idx = j * 1024 + t * 4;
        *(float4*)(Ws + idx) = *(const float4*)(W + idx);
    }
    int row0 = blockIdx.x * 16;
    {
        int idx = t * 4;
        int r = row0 + (idx >> 6);
        float4 v = make_float4(0.f, 0.f, 0.f, 0.f);
        if (r < N) v = *(const float4*)(x + (size_t)r * CCH + (idx & 63));
        *(float4*)(xsm + idx) = v;
    }
    __syncthreads();
    int lane = t & 63;
    int wv = t >> 6;
    float a0 = 0.f, a1 = 0.f, a2 = 0.f, a3 = 0.f;
    #pragma unroll
    for (int k = 0; k < CCH; ++k) {
        float w = Ws[k * CCH + lane];
        a0 += xsm[(wv * 4 + 0) * CCH + k] * w;
        a1 += xsm[(wv * 4 + 1) * CCH + k] * w;
        a2 += xsm[(wv * 4 + 2) * CCH + k] * w;
        a3 += xsm[(wv * 4 + 3) * CCH + k] * w;
    }
    const float* dv = dinv + c * N;
    float* hc = h + (size_t)c * N * CCH;
    int r = row0 + wv * 4;
    if (r + 0 < N) hc[(size_t)(r + 0) * CCH + lane] = a0 * dv[r + 0];
    if (r + 1 < N) hc[(size_t)(r + 1) * CCH + lane] = a1 * dv[r + 1];
    if (r + 2 < N) hc[(size_t)(r + 2) * CCH + lane] = a2 * dv[r + 2];
    if (r + 3 < N) hc[(size_t)(r + 3) * CCH + lane] = a3 * dv[r + 3];
}

// ---- CSR slot fill for all 3 convs ----
__global__ void k_fill_all(const int* __restrict__ e0, const int* __restrict__ e1,
                           const int* __restrict__ e2, int* __restrict__ pos,
                           int* __restrict__ sidx, int E, int N) {
    int t = blockIdx.x * blockDim.x + threadIdx.x;
    if (t >= 3 * E) return;
    int c = (t >= 2 * E) ? 2 : (t >= E) ? 1 : 0;
    int e = t - c * E;
    const int* ed = (c == 0) ? e0 : (c == 1) ? e1 : e2;
    int dst = ed[E + e];
    int src = ed[e];
    int slot = atomicAdd(&pos[c * N + dst], 1);
    sidx[(size_t)c * E + slot] = src;
}

// ---- pull helpers ----
__device__ inline float4 grp_reduce(float4 v) {
    v.x += __shfl_xor(v.x, 16, 64); v.y += __shfl_xor(v.y, 16, 64);
    v.z += __shfl_xor(v.z, 16, 64); v.w += __shfl_xor(v.w, 16, 64);
    v.x += __shfl_xor(v.x, 32, 64); v.y += __shfl_xor(v.y, 32, 64);
    v.z += __shfl_xor(v.z, 32, 64); v.w += __shfl_xor(v.w, 32, 64);
    return v;
}

// Sum h'[s,:] over this row's edge list. Wave = 4 groups x 16 lanes x float4;
// group g walks edges beg+g, beg+g+4, ... (2x unrolled -> 8 gathers in flight).
__device__ inline float4 gather_row(const float* __restrict__ h,
                                    const int* __restrict__ sidx,
                                    int beg, int end, int g, int l4) {
    float4 acc = make_float4(0.f, 0.f, 0.f, 0.f);
    int i = beg + g;
    for (; i + 4 < end; i += 8) {
        int s0 = sidx[i];
        int s1 = sidx[i + 4];
        float4 a = *(const float4*)(h + (size_t)s0 * CCH + l4);
        float4 b = *(const float4*)(h + (size_t)s1 * CCH + l4);
        acc.x += a.x + b.x; acc.y += a.y + b.y;
        acc.z += a.z + b.z; acc.w += a.w + b.w;
    }
    if (i < end) {
        int s0 = sidx[i];
        float4 a = *(const float4*)(h + (size_t)s0 * CCH + l4);
        acc.x += a.x; acc.y += a.y; acc.z += a.z; acc.w += a.w;
    }
    return acc;
}

// ---- fused pull: rows [0,N) = star (conv0+conv1+biases+selfloops),
//      rows [N,2N) = gal (conv2). Single non-atomic float4 store per row. ----
__global__ void __launch_bounds__(256) k_pull_all(const int* __restrict__ rs,
        const int* __restrict__ sidx, const float* __restrict__ h,
        const float* __restrict__ dinv,
        const float* __restrict__ b0, const float* __restrict__ b1,
        const float* __restrict__ b2,
        float* __restrict__ out, int N, int E) {
    int row = blockIdx.x * 4 + (threadIdx.x >> 6);
    if (row >= 2 * N) return;
    int lane = threadIdx.x & 63;
    int g = lane >> 4;
    int l4 = (lane & 15) * 4;
    int NP1 = N + 4;
    size_t NC = (size_t)N * CCH;
    if (row < N) {
        float dd0 = dinv[row], dd1 = dinv[N + row];
        float4 a0 = gather_row(h,      sidx,     rs[row],        rs[row + 1],        g, l4);
        float4 a1 = gather_row(h + NC, sidx + E, rs[NP1 + row],  rs[NP1 + row + 1],  g, l4);
        a0 = grp_reduce(a0);
        a1 = grp_reduce(a1);
        if (lane < 16) {
            float4 bv0 = *(const float4*)(b0 + l4);
            float4 bv1 = *(const float4*)(b1 + l4);
            float4 s0 = *(const float4*)(h + (size_t)row * CCH + l4);       // h' rows
            float4 s1 = *(const float4*)(h + NC + (size_t)row * CCH + l4);
            float4 o;
            o.x = (a0.x + s0.x) * dd0 + (a1.x + s1.x) * dd1 + bv0.x + bv1.x;
            o.y = (a0.y + s0.y) * dd0 + (a1.y + s1.y) * dd1 + bv0.y + bv1.y;
            o.z = (a0.z + s0.z) * dd0 + (a1.z + s1.z) * dd1 + bv0.z + bv1.z;
            o.w = (a0.w + s0.w) * dd0 + (a1.w + s1.w) * dd1 + bv0.w + bv1.w;
            *(float4*)(out + (size_t)row * CCH + l4) = o;
        }
    } else {
        int r = row - N;
        float dd2 = dinv[2 * N + r];
        const int* rs2 = rs + 2 * NP1;
        float4 a2 = gather_row(h + 2 * NC, sidx + 2 * (size_t)E,
                               rs2[r], rs2[r + 1], g, l4);
        a2 = grp_reduce(a2);
        if (lane < 16) {
            float4 bv2 = *(const float4*)(b2 + l4);
            float4 s2 = *(const float4*)(h + 2 * NC + (size_t)r * CCH + l4);
            float4 o;
            o.x = (a2.x + s2.x) * dd2 + bv2.x;
            o.y = (a2.y + s2.y) * dd2 + bv2.y;
            o.z = (a2.z + s2.z) * dd2 + bv2.z;
            o.w = (a2.w + s2.w) * dd2 + bv2.w;
            *(float4*)(out + (size_t)row * CCH + l4) = o;  // row in [N,2N) -> out_gal
        }
    }
}

extern "C" void kernel_launch(void* const* d_in, const int* in_sizes, int n_in,
                              void* d_out, int out_size, void* d_ws, size_t ws_size,
                              hipStream_t stream) {
    const float* x_star = (const float*)d_in[0];
    const float* x_gal  = (const float*)d_in[1];
    const int*   e_ssn  = (const int*)d_in[2];
    const int*   e_ssf  = (const int*)d_in[3];
    const int*   e_ggn  = (const int*)d_in[4];
    const float* W_ssn  = (const float*)d_in[5];
    const float* W_ssf  = (const float*)d_in[6];
    const float* W_ggn  = (const float*)d_in[7];
    const float* b_ssn  = (const float*)d_in[8];
    const float* b_ssf  = (const float*)d_in[9];
    const float* b_ggn  = (const float*)d_in[10];

    const int N  = in_sizes[0] / CCH;     // 50000
    const int E  = in_sizes[2] / 2;       // 1000000
    const size_t NC = (size_t)N * CCH;
    const int nb = (N + 1023) / 1024;     // blocks per conv for the scan

    // workspace layout (all 16B-aligned partitions)
    float* ws   = (float*)d_ws;
    float* h    = ws;                         // 3*NC floats (pre-scaled x@W)
    float* dinv = ws + 3 * NC;                // 3*N floats
    int*   deg  = (int*)(dinv + 3 * N);       // 3*N ints
    int*   pos  = deg + 3 * N;                // 3*N ints
    int*   sidx = pos + 3 * N;                // 3*E ints
    int*   bsum = sidx + (size_t)3 * E;       // 3*nb ints (padded to 160)
    int*   rs   = bsum + 160;                 // 3*(N+4) ints

    const int B = 256;

    k_zero<<<(3 * N + B - 1) / B, B, 0, stream>>>(deg, 3 * N);
    k_deg_all<<<(3 * E + B - 1) / B, B, 0, stream>>>(e_ssn, e_ssf, e_ggn, deg, E, N);
    k_scanA<<<3 * nb, B, 0, stream>>>(deg, dinv, rs, pos, bsum, N, nb);
    k_scanB<<<1, 192, 0, stream>>>(bsum, rs, nb, N, E);
    k_scanC<<<3 * nb, B, 0, stream>>>(rs, pos, bsum, N, nb);
    k_gemm_all<<<dim3((N + 15) / 16, 3), B, 0, stream>>>(x_star, x_gal,
                                                         W_ssn, W_ssf, W_ggn,
                                                         dinv, h, N);
    k_fill_all<<<(3 * E + B - 1) / B, B, 0, stream>>>(e_ssn, e_ssf, e_ggn,
                                                      pos, sidx, E, N);
    k_pull_all<<<(2 * N + 3) / 4, B, 0, stream>>>(rs, sidx, h, dinv,
                                                  b_ssn, b_ssf, b_ggn,
                                                  (float*)d_out, N, E);
}